// Round 6
// baseline (581.001 us; speedup 1.0000x reference)
//
#include <hip/hip_runtime.h>

typedef __attribute__((ext_vector_type(4))) float f32x4;
typedef __attribute__((ext_vector_type(8))) short s16x8;

__device__ __forceinline__ ushort f2bf(float f) {
  union { float f; uint u; } v; v.f = f;
  uint r = v.u + 0x7fffu + ((v.u >> 16) & 1u);
  return (ushort)(r >> 16);
}

__device__ __forceinline__ void glds16(const void* g, void* l) {
  __builtin_amdgcn_global_load_lds(
      (const __attribute__((address_space(1))) uint*)g,
      (__attribute__((address_space(3))) uint*)l, 16, 0, 0);
}

// swizzled index into a [rows][256] bf16 tile (16B-chunk XOR swizzle)
__device__ __forceinline__ int asidx(int row, int col) {
  return row*256 + ((((col>>3) ^ ((row&7)<<2)))<<3) + (col&7);
}
// swizzled index into a [rows][32] bf16 scratch tile
__device__ __forceinline__ int scridx(int row, int col) {
  return row*32 + ((((col>>3) ^ ((row>>2)&3)))<<3) + (col&7);
}

struct WSrc { const float* p[8]; };

// fp32 [*,256,256] (f-major) -> bf16 WT[n=g][k=f] with the k-chunk XOR swizzle
// baked in, so a LINEAR global_load_lds stage yields the swizzled LDS layout.
__global__ __launch_bounds__(256) void prep_weights(WSrc s, ushort* wq, ushort* wo) {
  int mm = blockIdx.x >> 6;          // 0..15: axis*4 + {0,1,2:qkv mats, 3:wo}
  int t  = blockIdx.x & 63;
  int a = mm >> 2, sub = mm & 3;
  const float* src = (sub < 3) ? (s.p[a*2] + sub*65536) : s.p[a*2+1];
  ushort*      dst = (sub < 3) ? (wq + (a*3 + sub)*65536) : (wo + a*65536);
  int gt = (t >> 3) * 32, ft = (t & 7) * 32;
  __shared__ float tile[32][33];
  int lx = threadIdx.x & 31, ly = threadIdx.x >> 5;
#pragma unroll
  for (int i = 0; i < 4; i++)
    tile[ly + i*8][lx] = src[(ft + ly + i*8)*256 + gt + lx];
  __syncthreads();
#pragma unroll
  for (int i = 0; i < 4; i++) {
    int n = gt + ly + i*8, col = ft + lx;
    dst[asidx(n, col)] = f2bf(tile[lx][ly + i*8]);
  }
}

template<int AXIS>
__device__ __forceinline__ int token_index(int blk, int row) {
  if (AXIS == 0) {                       // temporal: 8 seqs/block of len 8
    int seq = blk*8 + (row >> 3);
    int t = row & 7;
    int b = seq >> 12, n = seq & 4095;
    return (b*8 + t)*4096 + n;
  } else {
    int sid = blk*4 + (row >> 4);        // 4 seqs/block of len 16
    int bt = sid >> 8, lo = sid & 255, r = row & 15;
    if (AXIS == 1) { int hh = lo >> 4, ww = lo & 15; return bt*4096 + r*256 + hh*16 + ww; }
    if (AXIS == 2) { int dd = lo >> 4, ww = lo & 15; return bt*4096 + dd*256 + r*16 + ww; }
    { int dd = lo >> 4, hh = lo & 15; return bt*4096 + dd*256 + hh*16 + r; }
  }
}

template<int AXIS>
__global__ __launch_bounds__(256, 2) void axial_pass(
    const float* __restrict__ x0, const ushort* __restrict__ xb,
    const ushort* __restrict__ wqkvT, const float* __restrict__ bqkv,
    const ushort* __restrict__ woT, const float* __restrict__ bo,
    float* __restrict__ out, ushort* __restrict__ x1b) {

  __shared__ ushort Wbuf[2][8192];   // 32 KB: double-buffered 16 KB weight stages
  __shared__ ushort As[16384];       // 32 KB: X stage, then attn-out accumulation
  __shared__ ushort Scr[4][2048];    // 16 KB: PER-WAVE Q[0,512) K/P[512,1024) Vt[1024,2048)

  const int tid = threadIdx.x, blk = blockIdx.x;
  const int wv = tid >> 6, lane = tid & 63, llo = lane & 15, lhi = lane >> 4;
  ushort* Qs = Scr[wv];
  ushort* Ks = Qs + 512;                       // P aliases Ks after QK^T (same wave only)
  ushort* Vt = Qs + 1024;                      // V^T [32 d][32 tpad]
  const f32x4 fzero = {0.f, 0.f, 0.f, 0.f};
  const s16x8 szero = {0,0,0,0,0,0,0,0};

  // stage = 16 KB = one [32n][256k] weight slice; 4 glds/wave
  auto issue_stage = [&](int s) {
    const ushort* src = (s < 24) ? (wqkvT + (s % 3)*65536 + (s / 3)*8192)
                                 : (woT + (s - 24)*8192);
    const ushort* g = src + wv*2048 + lane*8;
    ushort* l = &Wbuf[s & 1][wv*2048];
#pragma unroll
    for (int i = 0; i < 4; i++) glds16(g + i*512, l + i*512);
  };

  // One barrier per stage: the same barrier that says "stage s's buffer is
  // consumable" also says "stage s-1's readers are done" -> safe to issue
  // s+1 into the other buffer. Counted vmcnt keeps prefetch in flight.
#define STAGE_SYNC(sn) do { \
    __builtin_amdgcn_sched_barrier(0); \
    asm volatile("s_waitcnt lgkmcnt(0)" ::: "memory"); \
    __builtin_amdgcn_sched_barrier(0); \
    __builtin_amdgcn_s_barrier(); \
    __builtin_amdgcn_sched_barrier(0); \
    if ((sn) < 32) { issue_stage(sn); \
      asm volatile("s_waitcnt vmcnt(4)" ::: "memory"); } \
    else { asm volatile("s_waitcnt vmcnt(0)" ::: "memory"); } \
    __builtin_amdgcn_sched_barrier(0); \
  } while (0)

  issue_stage(0);   // stage-0 weights load under the X staging below

  // ---- stage this wave's 16 X rows into As (wave-private rows) ----
  {
    int row = tid >> 2, q = tid & 3;   // row in [wv*16, wv*16+16)
    int tok = token_index<AXIS>(blk, row);
    if (AXIS == 0) {
      const float4* s4 = (const float4*)(x0 + (size_t)tok*256 + q*64);
#pragma unroll
      for (int c2 = 0; c2 < 8; c2++) {
        float4 v0 = s4[c2*2], v1 = s4[c2*2 + 1];
        s16x8 o;
        o[0] = (short)f2bf(v0.x); o[1] = (short)f2bf(v0.y);
        o[2] = (short)f2bf(v0.z); o[3] = (short)f2bf(v0.w);
        o[4] = (short)f2bf(v1.x); o[5] = (short)f2bf(v1.y);
        o[6] = (short)f2bf(v1.z); o[7] = (short)f2bf(v1.w);
        *(s16x8*)(As + asidx(row, (q*8 + c2)*8)) = o;
      }
    } else {
      const s16x8* s8 = (const s16x8*)(xb + (size_t)tok*256 + q*64);
#pragma unroll
      for (int c2 = 0; c2 < 8; c2++)
        *(s16x8*)(As + asidx(row, (q*8 + c2)*8)) = s8[c2];
    }
  }
  // zero this wave's V^T k-pad (cols 16..31) once
  {
    int row = lane >> 1, cc = 2 + (lane & 1);
    *(s16x8*)(Vt + row*32 + ((cc ^ ((row>>2)&3))<<3)) = szero;
  }

  // ---- A-fragments to registers (own rows; in-order per-wave LDS) ----
  s16x8 af[8];
  const int xrow = wv*16 + llo;
#pragma unroll
  for (int ks = 0; ks < 8; ks++)
    af[ks] = *(const s16x8*)(As + asidx(xrow, (ks*4 + lhi)*8));

  // full-width projection: 32 n-rows (2 chunks of 16) x 256 k = 16 MFMA
  auto proj2 = [&](int sb, f32x4& c0, f32x4& c1) {
    const ushort* buf = Wbuf[sb];
    const int sw = ((llo & 7) << 2);
#pragma unroll
    for (int ks = 0; ks < 8; ks++) {
      int cs = (((ks*4 + lhi) ^ sw) << 3);
      s16x8 b0 = *(const s16x8*)(buf + llo*256 + cs);
      s16x8 b1 = *(const s16x8*)(buf + (16 + llo)*256 + cs);
      c0 = __builtin_amdgcn_mfma_f32_16x16x32_bf16(af[ks], b0, c0, 0, 0, 0);
      c1 = __builtin_amdgcn_mfma_f32_16x16x32_bf16(af[ks], b1, c1, 0, 0, 0);
    }
  };

  // ================= head loop: stage s = 3h+m =================
#pragma unroll 1
  for (int h = 0; h < 8; h++) {
#pragma unroll
    for (int m = 0; m < 3; m++) {
      const int s = 3*h + m;
      STAGE_SYNC(s + 1);
      f32x4 c0 = fzero, c1 = fzero;
      proj2(s & 1, c0, c1);
      float b0v = bqkv[m*256 + h*32 + llo];
      float b1v = bqkv[m*256 + h*32 + 16 + llo];
      if (m == 0) {
#pragma unroll
        for (int r = 0; r < 4; r++) {
          Qs[scridx(lhi*4 + r, llo)]      = f2bf(c0[r] + b0v);
          Qs[scridx(lhi*4 + r, 16 + llo)] = f2bf(c1[r] + b1v);
        }
      } else if (m == 1) {
#pragma unroll
        for (int r = 0; r < 4; r++) {
          Ks[scridx(lhi*4 + r, llo)]      = f2bf(c0[r] + b0v);
          Ks[scridx(lhi*4 + r, 16 + llo)] = f2bf(c1[r] + b1v);
        }
      } else {
#pragma unroll
        for (int r = 0; r < 4; r++) {      // V^T [d][t]
          Vt[scridx(llo, lhi*4 + r)]      = f2bf(c0[r] + b0v);
          Vt[scridx(16 + llo, lhi*4 + r)] = f2bf(c1[r] + b1v);
        }
        // ---- attention (all scratch wave-private; in-order LDS) ----
        s16x8 aq = *(const s16x8*)(Qs + scridx(llo, lhi*8));
        s16x8 bk = *(const s16x8*)(Ks + scridx(llo, lhi*8));
        f32x4 sc = __builtin_amdgcn_mfma_f32_16x16x32_bf16(aq, bk, fzero, 0, 0, 0);
#pragma unroll
        for (int r = 0; r < 4; r++) {
          float sv = sc[r] * 0.17677669529663689f;
          if (AXIS == 0) {   // two packed length-8 seqs: block-diagonal mask
            int srow = lhi*4 + r;
            if ((srow >> 3) != (llo >> 3)) sv = -1e30f;
          }
          float mx = sv;
          mx = fmaxf(mx, __shfl_xor(mx, 1));
          mx = fmaxf(mx, __shfl_xor(mx, 2));
          mx = fmaxf(mx, __shfl_xor(mx, 4));
          mx = fmaxf(mx, __shfl_xor(mx, 8));
          float e = __expf(sv - mx);
          float sm = e;
          sm += __shfl_xor(sm, 1);
          sm += __shfl_xor(sm, 2);
          sm += __shfl_xor(sm, 4);
          sm += __shfl_xor(sm, 8);
          Ks[scridx(lhi*4 + r, llo)] = f2bf(e * __builtin_amdgcn_rcpf(sm)); // P
        }
        // PV (P k-pad garbage x V^T zero-pad = 0)
        s16x8 ap = *(const s16x8*)(Ks + scridx(llo, lhi*8));
        s16x8 bv0 = *(const s16x8*)(Vt + scridx(llo, lhi*8));
        s16x8 bv1 = *(const s16x8*)(Vt + scridx(16 + llo, lhi*8));
        f32x4 o0 = __builtin_amdgcn_mfma_f32_16x16x32_bf16(ap, bv0, fzero, 0, 0, 0);
        f32x4 o1 = __builtin_amdgcn_mfma_f32_16x16x32_bf16(ap, bv1, fzero, 0, 0, 0);
#pragma unroll
        for (int r = 0; r < 4; r++) {
          As[asidx(wv*16 + lhi*4 + r, h*32 + llo)]      = f2bf(o0[r]);
          As[asidx(wv*16 + lhi*4 + r, h*32 + 16 + llo)] = f2bf(o1[r]);
        }
      }
    }
  }

  // ================= out-proj: stages 24..31 =================
  f32x4 acc[16];
#pragma unroll 1
  for (int st = 0; st < 8; st++) {
    STAGE_SYNC(25 + st);
    if (st == 0) {
      // A-fragments = own attn-out rows (all heads); in-order per-wave LDS
#pragma unroll
      for (int ks = 0; ks < 8; ks++)
        af[ks] = *(const s16x8*)(As + asidx(xrow, (ks*4 + lhi)*8));
#pragma unroll
      for (int i = 0; i < 16; i++) acc[i] = fzero;
    }
    {
      const ushort* buf = Wbuf[st & 1];
      const int sw = ((llo & 7) << 2);
#pragma unroll
      for (int ks = 0; ks < 8; ks++) {
        int cs = (((ks*4 + lhi) ^ sw) << 3);
        s16x8 b0 = *(const s16x8*)(buf + llo*256 + cs);
        s16x8 b1 = *(const s16x8*)(buf + (16 + llo)*256 + cs);
        acc[st*2]   = __builtin_amdgcn_mfma_f32_16x16x32_bf16(af[ks], b0, acc[st*2], 0, 0, 0);
        acc[st*2+1] = __builtin_amdgcn_mfma_f32_16x16x32_bf16(af[ks], b1, acc[st*2+1], 0, 0, 0);
      }
    }
  }

  // ---- epilogue: +bo, residual ----
#pragma unroll
  for (int r = 0; r < 4; r++) {
    int row = wv*16 + lhi*4 + r;
    int tok = token_index<AXIS>(blk, row);
    size_t base = (size_t)tok*256;
#pragma unroll
    for (int nt = 0; nt < 16; nt++) {
      int f = (nt >> 1)*32 + (nt & 1)*16 + llo;
      float v = acc[nt][r] + bo[f];
      if (AXIS == 0) {
        v += x0[base + f];
        out[base + f] = v;          // x1 (fp32)
        x1b[base + f] = f2bf(v);    // x1 (bf16) for spatial passes
      } else {
        out[base + f] += v;         // accumulate axis contribution
      }
    }
  }
#undef STAGE_SYNC
}

extern "C" void kernel_launch(void* const* d_in, const int* in_sizes, int n_in,
                              void* d_out, int out_size, void* d_ws, size_t ws_size,
                              hipStream_t stream) {
  const float* x = (const float*)d_in[0];
  ushort* wq  = (ushort*)d_ws;                 // 4*3*65536 bf16
  ushort* wo  = wq + 4*3*65536;                // 4*65536 bf16
  ushort* x1b = wo + 4*65536;                  // 65536*256 bf16
  float* out = (float*)d_out;

  WSrc wsrc;
  wsrc.p[0] = (const float*)d_in[1];  wsrc.p[1] = (const float*)d_in[3];
  wsrc.p[2] = (const float*)d_in[5];  wsrc.p[3] = (const float*)d_in[7];
  wsrc.p[4] = (const float*)d_in[9];  wsrc.p[5] = (const float*)d_in[11];
  wsrc.p[6] = (const float*)d_in[13]; wsrc.p[7] = (const float*)d_in[15];
  prep_weights<<<dim3(1024), dim3(256), 0, stream>>>(wsrc, wq, wo);

  const float* bq_t = (const float*)d_in[2];  const float* bo_t = (const float*)d_in[4];
  const float* bq_d = (const float*)d_in[6];  const float* bo_d = (const float*)d_in[8];
  const float* bq_h = (const float*)d_in[10]; const float* bo_h = (const float*)d_in[12];
  const float* bq_w = (const float*)d_in[14]; const float* bo_w = (const float*)d_in[16];

  axial_pass<0><<<dim3(1024), dim3(256), 0, stream>>>(x, nullptr, wq + 0*3*65536, bq_t, wo + 0*65536, bo_t, out, x1b);
  axial_pass<1><<<dim3(1024), dim3(256), 0, stream>>>(nullptr, x1b, wq + 1*3*65536, bq_d, wo + 1*65536, bo_d, out, nullptr);
  axial_pass<2><<<dim3(1024), dim3(256), 0, stream>>>(nullptr, x1b, wq + 2*3*65536, bq_h, wo + 2*65536, bo_h, out, nullptr);
  axial_pass<3><<<dim3(1024), dim3(256), 0, stream>>>(nullptr, x1b, wq + 3*3*65536, bq_w, wo + 3*65536, bo_w, out, nullptr);
}

// Round 7
// 435.792 us; speedup vs baseline: 1.3332x; 1.3332x over previous
//
#include <hip/hip_runtime.h>

typedef __attribute__((ext_vector_type(4))) float f32x4;
typedef __attribute__((ext_vector_type(8))) short s16x8;

__device__ __forceinline__ ushort f2bf(float f) {
  union { float f; uint u; } v; v.f = f;
  uint r = v.u + 0x7fffu + ((v.u >> 16) & 1u);
  return (ushort)(r >> 16);
}

__device__ __forceinline__ void glds16(const void* g, void* l) {
  __builtin_amdgcn_global_load_lds(
      (const __attribute__((address_space(1))) uint*)g,
      (__attribute__((address_space(3))) uint*)l, 16, 0, 0);
}

// swizzled index into a [rows][256] bf16 tile (16B-chunk XOR swizzle)
__device__ __forceinline__ int asidx(int row, int col) {
  return row*256 + ((((col>>3) ^ ((row&7)<<2)))<<3) + (col&7);
}
// swizzled index into a [rows][32] bf16 scratch tile
__device__ __forceinline__ int scridx(int row, int col) {
  return row*32 + ((((col>>3) ^ ((row>>2)&3)))<<3) + (col&7);
}

struct WSrc { const float* p[8]; };

// fp32 [*,256,256] (f-major) -> bf16 WT[n=g][k=f] with the k-chunk XOR swizzle
// baked in, so a LINEAR global_load_lds stage yields the swizzled LDS layout.
__global__ __launch_bounds__(256) void prep_weights(WSrc s, ushort* wq, ushort* wo) {
  int mm = blockIdx.x >> 6;          // 0..15: axis*4 + {0,1,2:qkv mats, 3:wo}
  int t  = blockIdx.x & 63;
  int a = mm >> 2, sub = mm & 3;
  const float* src = (sub < 3) ? (s.p[a*2] + sub*65536) : s.p[a*2+1];
  ushort*      dst = (sub < 3) ? (wq + (a*3 + sub)*65536) : (wo + a*65536);
  int gt = (t >> 3) * 32, ft = (t & 7) * 32;
  __shared__ float tile[32][33];
  int lx = threadIdx.x & 31, ly = threadIdx.x >> 5;
#pragma unroll
  for (int i = 0; i < 4; i++)
    tile[ly + i*8][lx] = src[(ft + ly + i*8)*256 + gt + lx];
  __syncthreads();
#pragma unroll
  for (int i = 0; i < 4; i++) {
    int n = gt + ly + i*8, col = ft + lx;
    dst[asidx(n, col)] = f2bf(tile[lx][ly + i*8]);
  }
}

template<int AXIS>
__device__ __forceinline__ int token_index(int blk, int row) {
  if (AXIS == 0) {                       // temporal: 8 seqs/block of len 8
    int seq = blk*8 + (row >> 3);
    int t = row & 7;
    int b = seq >> 12, n = seq & 4095;
    return (b*8 + t)*4096 + n;
  } else {
    int sid = blk*4 + (row >> 4);        // 4 seqs/block of len 16
    int bt = sid >> 8, lo = sid & 255, r = row & 15;
    if (AXIS == 1) { int hh = lo >> 4, ww = lo & 15; return bt*4096 + r*256 + hh*16 + ww; }
    if (AXIS == 2) { int dd = lo >> 4, ww = lo & 15; return bt*4096 + dd*256 + r*16 + ww; }
    { int dd = lo >> 4, hh = lo & 15; return bt*4096 + dd*256 + hh*16 + r; }
  }
}

// LDS-write publication fence (raw s_barrier does NOT drain ds_writes).
#define PUB_BARRIER() do { \
    __builtin_amdgcn_sched_barrier(0); \
    asm volatile("s_waitcnt lgkmcnt(0)" ::: "memory"); \
    __builtin_amdgcn_sched_barrier(0); \
    __builtin_amdgcn_s_barrier(); \
    __builtin_amdgcn_sched_barrier(0); } while (0)

template<int AXIS>
__global__ __launch_bounds__(512, 4) void axial_pass(
    const float* __restrict__ x0, const ushort* __restrict__ xb,
    const ushort* __restrict__ wqkvT, const float* __restrict__ bqkv,
    const ushort* __restrict__ woT, const float* __restrict__ bo,
    float* __restrict__ out, ushort* __restrict__ x1b) {

  __shared__ ushort Wbuf[2][8192];   // 32 KB: double-buffered 16 KB weight stages
  __shared__ ushort As[16384];       // 32 KB: X stage, then attn-out accumulation
  __shared__ ushort Scr[4][2048];    // 16 KB: per-pair Q[0,512) K/P[512,1024) Vt[1024,2048)

  const int tid = threadIdx.x, blk = blockIdx.x;
  const int wv = tid >> 6, lane = tid & 63, llo = lane & 15, lhi = lane >> 4;
  const int pr = wv >> 1, half = wv & 1;       // pair id, N-half
  const int rr = half*16 + llo;                // row-in-stage / col-in-head
  ushort* Qs = Scr[pr];
  ushort* Ks = Qs + 512;                       // P aliases Ks after QK^T
  ushort* Vt = Qs + 1024;                      // V^T [32 d][32 tpad]
  const f32x4 fzero = {0.f, 0.f, 0.f, 0.f};
  const s16x8 szero = {0,0,0,0,0,0,0,0};

  auto issue_stage = [&](int s) {
    const ushort* src = (s < 24) ? (wqkvT + (s % 3)*65536 + (s / 3)*8192)
                                 : (woT + (s - 24)*8192);
    const ushort* g = src + wv*1024 + lane*8;
    ushort* l = &Wbuf[s & 1][wv*1024];
    glds16(g, l);
    glds16(g + 512, l + 512);
  };

  // Single barrier per stage, COLLECTIVE order: drain own vmcnt+lgkm BEFORE
  // the barrier (so post-barrier, every wave's stage loads have landed and
  // every scratch write is published), issue the next stage AFTER it (its
  // buffer was last read in compute s-1, which all waves finished).
#define STAGE_SYNC(sn) do { \
    __builtin_amdgcn_sched_barrier(0); \
    asm volatile("s_waitcnt vmcnt(0) lgkmcnt(0)" ::: "memory"); \
    __builtin_amdgcn_sched_barrier(0); \
    __builtin_amdgcn_s_barrier(); \
    __builtin_amdgcn_sched_barrier(0); \
    if ((sn) < 32) issue_stage(sn); \
  } while (0)

  issue_stage(0);   // stage-0 weights load under the X staging below

  // ---- stage X tile into As (swizzled; conflict-free stride-8 chunk map) ----
  {
    int row = tid >> 3, j = tid & 7;
    int tok = token_index<AXIS>(blk, row);
    if (AXIS == 0) {
      const float4* s4 = (const float4*)(x0 + (size_t)tok*256);
#pragma unroll
      for (int i = 0; i < 4; i++) {
        int c = j + 8*i;
        float4 v0 = s4[c*2], v1 = s4[c*2 + 1];
        s16x8 o;
        o[0] = (short)f2bf(v0.x); o[1] = (short)f2bf(v0.y);
        o[2] = (short)f2bf(v0.z); o[3] = (short)f2bf(v0.w);
        o[4] = (short)f2bf(v1.x); o[5] = (short)f2bf(v1.y);
        o[6] = (short)f2bf(v1.z); o[7] = (short)f2bf(v1.w);
        *(s16x8*)(As + asidx(row, c*8)) = o;
      }
    } else {
      const s16x8* s8 = (const s16x8*)(xb + (size_t)tok*256);
#pragma unroll
      for (int i = 0; i < 4; i++) {
        int c = j + 8*i;
        *(s16x8*)(As + asidx(row, c*8)) = s8[c];
      }
    }
  }
  // zero this wave's V^T k-pad (cols 16..31) once
  {
    int row = half*16 + (lane >> 2);
    int cc = 2 + (lane & 1);
    *(s16x8*)(Vt + row*32 + ((cc ^ ((row>>2)&3))<<3)) = szero;
  }
  __syncthreads();   // full drain: X + zero-pad + stage-0 glds all published

  // ---- A-fragments to registers (reused for all 24 qkv stages) ----
  s16x8 af[8];
  const int xrow = pr*16 + llo;
#pragma unroll
  for (int ks = 0; ks < 8; ks++)
    af[ks] = *(const s16x8*)(As + asidx(xrow, (ks*4 + lhi)*8));

  auto proj = [&](int sb) -> f32x4 {
    const ushort* buf = Wbuf[sb];
    f32x4 c = fzero;
#pragma unroll
    for (int ks = 0; ks < 8; ks++) {
      s16x8 bv = *(const s16x8*)(buf + rr*256 + ((((ks*4+lhi) ^ ((rr&7)<<2)))<<3));
      c = __builtin_amdgcn_mfma_f32_16x16x32_bf16(af[ks], bv, c, 0, 0, 0);
    }
    return c;
  };

  // ================= head loop: stages 3h (Q), 3h+1 (K), 3h+2 (V+attn) ======
#pragma unroll 1
  for (int h = 0; h < 8; h++) {
    // ---- Q ----
    STAGE_SYNC(3*h + 1);
    {
      f32x4 c = proj((3*h) & 1);
      float bias = bqkv[0*256 + h*32 + rr];
#pragma unroll
      for (int r = 0; r < 4; r++)
        Qs[scridx(lhi*4 + r, rr)] = f2bf(c[r] + bias);
    }
    // ---- K ----
    STAGE_SYNC(3*h + 2);
    {
      f32x4 c = proj((3*h + 1) & 1);
      float bias = bqkv[1*256 + h*32 + rr];
#pragma unroll
      for (int r = 0; r < 4; r++)
        Ks[scridx(lhi*4 + r, rr)] = f2bf(c[r] + bias);
    }
    // ---- V + attention ----
    STAGE_SYNC(3*h + 3);
    {
      f32x4 c = proj((3*h + 2) & 1);
      float bias = bqkv[2*256 + h*32 + rr];
#pragma unroll
      for (int r = 0; r < 4; r++)
        Vt[scridx(rr, lhi*4 + r)] = f2bf(c[r] + bias);   // V^T [d][t]

      // scores = Q K^T / sqrt(32); wave-parallel softmax (both pair waves
      // compute identical P — benign identical-write race)
      s16x8 aq = *(const s16x8*)(Qs + scridx(llo, lhi*8));
      s16x8 bk = *(const s16x8*)(Ks + scridx(llo, lhi*8));
      f32x4 sc = __builtin_amdgcn_mfma_f32_16x16x32_bf16(aq, bk, fzero, 0, 0, 0);

      // Publication + ordering fence: (a) our Vt stores commit, (b) every
      // wave's aq/bk reads are consumed before any wave's P-store below
      // overwrites Ks (the round-3 race).
      PUB_BARRIER();

#pragma unroll
      for (int r = 0; r < 4; r++) {
        float s = sc[r] * 0.17677669529663689f;
        if (AXIS == 0) {   // two packed length-8 seqs: block-diagonal mask
          int srow = lhi*4 + r;
          if ((srow >> 3) != (llo >> 3)) s = -1e30f;
        }
        float mx = s;
        mx = fmaxf(mx, __shfl_xor(mx, 1));
        mx = fmaxf(mx, __shfl_xor(mx, 2));
        mx = fmaxf(mx, __shfl_xor(mx, 4));
        mx = fmaxf(mx, __shfl_xor(mx, 8));
        float e = __expf(s - mx);
        float sm = e;
        sm += __shfl_xor(sm, 1);
        sm += __shfl_xor(sm, 2);
        sm += __shfl_xor(sm, 4);
        sm += __shfl_xor(sm, 8);
        Ks[scridx(lhi*4 + r, llo)] = f2bf(e * __builtin_amdgcn_rcpf(sm)); // P
      }
      // PV: own d-half only (P k-pad garbage × V^T zero-pad = 0)
      s16x8 ap = *(const s16x8*)(Ks + scridx(llo, lhi*8));
      s16x8 bv = *(const s16x8*)(Vt + scridx(rr, lhi*8));
      f32x4 o = __builtin_amdgcn_mfma_f32_16x16x32_bf16(ap, bv, fzero, 0, 0, 0);
#pragma unroll
      for (int r = 0; r < 4; r++)
        As[asidx(pr*16 + lhi*4 + r, h*32 + rr)] = f2bf(o[r]);
    }
  }

  // ================= out-proj: stages 24..31, acc += A @ Wo ==================
  f32x4 acc[8];
#pragma unroll 1
  for (int st = 0; st < 8; st++) {
    STAGE_SYNC(25 + st);
    if (st == 0) {
      // reload A-fragments = per-token attn outputs (all heads)
#pragma unroll
      for (int ks = 0; ks < 8; ks++)
        af[ks] = *(const s16x8*)(As + asidx(xrow, (ks*4 + lhi)*8));
#pragma unroll
      for (int i = 0; i < 8; i++) acc[i] = fzero;
    }
    {
      const ushort* buf = Wbuf[st & 1];
#pragma unroll
      for (int ks = 0; ks < 8; ks++) {
        s16x8 bw = *(const s16x8*)(buf + rr*256 + ((((ks*4+lhi) ^ ((rr&7)<<2)))<<3));
        acc[st] = __builtin_amdgcn_mfma_f32_16x16x32_bf16(af[ks], bw, acc[st], 0, 0, 0);
      }
    }
  }

  // ---- epilogue: +bo, residual ----
#pragma unroll
  for (int r = 0; r < 4; r++) {
    int row = pr*16 + lhi*4 + r;
    int tok = token_index<AXIS>(blk, row);
    size_t base = (size_t)tok*256;
#pragma unroll
    for (int st = 0; st < 8; st++) {
      int f = st*32 + half*16 + llo;
      float v = acc[st][r] + bo[f];
      if (AXIS == 0) {
        v += x0[base + f];
        out[base + f] = v;          // x1 (fp32)
        x1b[base + f] = f2bf(v);    // x1 (bf16) for spatial passes
      } else {
        out[base + f] += v;         // accumulate axis contribution
      }
    }
  }
#undef STAGE_SYNC
}

extern "C" void kernel_launch(void* const* d_in, const int* in_sizes, int n_in,
                              void* d_out, int out_size, void* d_ws, size_t ws_size,
                              hipStream_t stream) {
  const float* x = (const float*)d_in[0];
  ushort* wq  = (ushort*)d_ws;                 // 4*3*65536 bf16
  ushort* wo  = wq + 4*3*65536;                // 4*65536 bf16
  ushort* x1b = wo + 4*65536;                  // 65536*256 bf16
  float* out = (float*)d_out;

  WSrc wsrc;
  wsrc.p[0] = (const float*)d_in[1];  wsrc.p[1] = (const float*)d_in[3];
  wsrc.p[2] = (const float*)d_in[5];  wsrc.p[3] = (const float*)d_in[7];
  wsrc.p[4] = (const float*)d_in[9];  wsrc.p[5] = (const float*)d_in[11];
  wsrc.p[6] = (const float*)d_in[13]; wsrc.p[7] = (const float*)d_in[15];
  prep_weights<<<dim3(1024), dim3(256), 0, stream>>>(wsrc, wq, wo);

  const float* bq_t = (const float*)d_in[2];  const float* bo_t = (const float*)d_in[4];
  const float* bq_d = (const float*)d_in[6];  const float* bo_d = (const float*)d_in[8];
  const float* bq_h = (const float*)d_in[10]; const float* bo_h = (const float*)d_in[12];
  const float* bq_w = (const float*)d_in[14]; const float* bo_w = (const float*)d_in[16];

  axial_pass<0><<<dim3(1024), dim3(512), 0, stream>>>(x, nullptr, wq + 0*3*65536, bq_t, wo + 0*65536, bo_t, out, x1b);
  axial_pass<1><<<dim3(1024), dim3(512), 0, stream>>>(nullptr, x1b, wq + 1*3*65536, bq_d, wo + 1*65536, bo_d, out, nullptr);
  axial_pass<2><<<dim3(1024), dim3(512), 0, stream>>>(nullptr, x1b, wq + 2*3*65536, bq_h, wo + 2*65536, bo_h, out, nullptr);
  axial_pass<3><<<dim3(1024), dim3(512), 0, stream>>>(nullptr, x1b, wq + 3*3*65536, bq_w, wo + 3*65536, bo_w, out, nullptr);
}

// Round 8
// 402.836 us; speedup vs baseline: 1.4423x; 1.0818x over previous
//
#include <hip/hip_runtime.h>

typedef __attribute__((ext_vector_type(4))) float f32x4;
typedef __attribute__((ext_vector_type(8))) short s16x8;

__device__ __forceinline__ ushort f2bf(float f) {
  union { float f; uint u; } v; v.f = f;
  uint r = v.u + 0x7fffu + ((v.u >> 16) & 1u);
  return (ushort)(r >> 16);
}

__device__ __forceinline__ void glds16(const void* g, void* l) {
  __builtin_amdgcn_global_load_lds(
      (const __attribute__((address_space(1))) uint*)g,
      (__attribute__((address_space(3))) uint*)l, 16, 0, 0);
}

// swizzled index into a [rows][256] bf16 tile: full (row&7) chunk-XOR so all
// 8 row-groups of a wave's b128 reads land on distinct bank groups.
__device__ __forceinline__ int asidx(int row, int col) {
  return row*256 + ((((col>>3) ^ (row & 7)))<<3) + (col&7);
}
// swizzled index into a [rows][32] bf16 scratch tile
__device__ __forceinline__ int scridx(int row, int col) {
  return row*32 + ((((col>>3) ^ ((row>>2)&3)))<<3) + (col&7);
}
// epilogue fp32 [64][256] staging: XOR bits 2-4 of f by row&7 (float4-safe)
__device__ __forceinline__ int epidx(int row, int f) {
  return row*256 + (f ^ ((row & 7) << 2));
}

struct WSrc { const float* p[8]; };

// fp32 [*,256,256] (f-major) -> bf16 WT[n=g][k=f] with the chunk XOR swizzle
// baked in, so a LINEAR global_load_lds stage yields the swizzled LDS layout.
__global__ __launch_bounds__(256) void prep_weights(WSrc s, ushort* wq, ushort* wo) {
  int mm = blockIdx.x >> 6;          // 0..15: axis*4 + {0,1,2:qkv mats, 3:wo}
  int t  = blockIdx.x & 63;
  int a = mm >> 2, sub = mm & 3;
  const float* src = (sub < 3) ? (s.p[a*2] + sub*65536) : s.p[a*2+1];
  ushort*      dst = (sub < 3) ? (wq + (a*3 + sub)*65536) : (wo + a*65536);
  int gt = (t >> 3) * 32, ft = (t & 7) * 32;
  __shared__ float tile[32][33];
  int lx = threadIdx.x & 31, ly = threadIdx.x >> 5;
#pragma unroll
  for (int i = 0; i < 4; i++)
    tile[ly + i*8][lx] = src[(ft + ly + i*8)*256 + gt + lx];
  __syncthreads();
#pragma unroll
  for (int i = 0; i < 4; i++) {
    int n = gt + ly + i*8, col = ft + lx;
    dst[asidx(n, col)] = f2bf(tile[lx][ly + i*8]);
  }
}

template<int AXIS>
__device__ __forceinline__ int token_index(int blk, int row) {
  if (AXIS == 0) {                       // temporal: 8 seqs/block of len 8
    int seq = blk*8 + (row >> 3);
    int t = row & 7;
    int b = seq >> 12, n = seq & 4095;
    return (b*8 + t)*4096 + n;
  } else {
    int sid = blk*4 + (row >> 4);        // 4 seqs/block of len 16
    int bt = sid >> 8, lo = sid & 255, r = row & 15;
    if (AXIS == 1) { int hh = lo >> 4, ww = lo & 15; return bt*4096 + r*256 + hh*16 + ww; }
    if (AXIS == 2) { int dd = lo >> 4, ww = lo & 15; return bt*4096 + dd*256 + r*16 + ww; }
    { int dd = lo >> 4, hh = lo & 15; return bt*4096 + dd*256 + hh*16 + r; }
  }
}

// LDS-write publication fence (raw s_barrier does NOT drain ds_writes).
#define PUB_BARRIER() do { \
    __builtin_amdgcn_sched_barrier(0); \
    asm volatile("s_waitcnt lgkmcnt(0)" ::: "memory"); \
    __builtin_amdgcn_sched_barrier(0); \
    __builtin_amdgcn_s_barrier(); \
    __builtin_amdgcn_sched_barrier(0); } while (0)

template<int AXIS>
__global__ __launch_bounds__(512, 4) void axial_pass(
    const float* __restrict__ x0, const ushort* __restrict__ xb,
    const ushort* __restrict__ wqkvT, const float* __restrict__ bqkv,
    const ushort* __restrict__ woT, const float* __restrict__ bo,
    float* __restrict__ out, ushort* __restrict__ x1b) {

  // 80 KB, manually partitioned so the epilogue can alias Wbuf+As as fp32.
  __shared__ ushort smem[40960];
  ushort* Wb0 = smem;                // 16 KB weight stage buffer 0
  ushort* Wb1 = smem + 8192;         // 16 KB weight stage buffer 1
  ushort* As  = smem + 16384;        // 32 KB: X stage, then attn-out
  ushort* ScrB = smem + 32768;       // 16 KB: per-pair scratch

  const int tid = threadIdx.x, blk = blockIdx.x;
  const int wv = tid >> 6, lane = tid & 63, llo = lane & 15, lhi = lane >> 4;
  const int pr = wv >> 1, half = wv & 1;       // pair id, N-half
  const int rr = half*16 + llo;                // row-in-stage / col-in-head
  ushort* Qs = ScrB + pr*2048;
  ushort* Ks = Qs + 512;                       // P aliases Ks after QK^T
  ushort* Vt = Qs + 1024;                      // V^T [32 d][32 tpad]
  const f32x4 fzero = {0.f, 0.f, 0.f, 0.f};
  const s16x8 szero = {0,0,0,0,0,0,0,0};

  auto issue_stage = [&](int s) {
    const ushort* src = (s < 24) ? (wqkvT + (s % 3)*65536 + (s / 3)*8192)
                                 : (woT + (s - 24)*8192);
    const ushort* g = src + wv*1024 + lane*8;
    ushort* l = ((s & 1) ? Wb1 : Wb0) + wv*1024;
    glds16(g, l);
    glds16(g + 512, l + 512);
  };

  // Single barrier per stage, collective order: drain own vmcnt+lgkm BEFORE
  // the barrier, issue the next stage AFTER it (proven correct in round 7).
#define STAGE_SYNC(sn) do { \
    __builtin_amdgcn_sched_barrier(0); \
    asm volatile("s_waitcnt vmcnt(0) lgkmcnt(0)" ::: "memory"); \
    __builtin_amdgcn_sched_barrier(0); \
    __builtin_amdgcn_s_barrier(); \
    __builtin_amdgcn_sched_barrier(0); \
    if ((sn) < 32) issue_stage(sn); \
  } while (0)

  issue_stage(0);   // stage-0 weights load under the X staging below

  // ---- stage X tile into As (swizzled) ----
  {
    int row = tid >> 3, j = tid & 7;
    int tok = token_index<AXIS>(blk, row);
    if (AXIS == 0) {
      const float4* s4 = (const float4*)(x0 + (size_t)tok*256);
#pragma unroll
      for (int i = 0; i < 4; i++) {
        int c = j + 8*i;
        float4 v0 = s4[c*2], v1 = s4[c*2 + 1];
        s16x8 o;
        o[0] = (short)f2bf(v0.x); o[1] = (short)f2bf(v0.y);
        o[2] = (short)f2bf(v0.z); o[3] = (short)f2bf(v0.w);
        o[4] = (short)f2bf(v1.x); o[5] = (short)f2bf(v1.y);
        o[6] = (short)f2bf(v1.z); o[7] = (short)f2bf(v1.w);
        *(s16x8*)(As + asidx(row, c*8)) = o;
      }
    } else {
      const s16x8* s8 = (const s16x8*)(xb + (size_t)tok*256);
#pragma unroll
      for (int i = 0; i < 4; i++) {
        int c = j + 8*i;
        *(s16x8*)(As + asidx(row, c*8)) = s8[c];
      }
    }
  }
  // zero this wave's V^T k-pad (cols 16..31) once
  {
    int row = half*16 + (lane >> 2);
    int cc = 2 + (lane & 1);
    *(s16x8*)(Vt + row*32 + ((cc ^ ((row>>2)&3))<<3)) = szero;
  }
  __syncthreads();   // full drain: X + zero-pad + stage-0 glds all published

  // ---- A-fragments to registers (reused for all 24 qkv stages) ----
  s16x8 af[8];
  const int xrow = pr*16 + llo;
#pragma unroll
  for (int ks = 0; ks < 8; ks++)
    af[ks] = *(const s16x8*)(As + asidx(xrow, (ks*4 + lhi)*8));

  // split accumulator chains (2x4) to halve serial MFMA latency
  auto proj = [&](int sb) -> f32x4 {
    const ushort* buf = sb ? Wb1 : Wb0;
    f32x4 ca = fzero, cb = fzero;
    __builtin_amdgcn_s_setprio(1);
#pragma unroll
    for (int ks = 0; ks < 4; ks++) {
      s16x8 b0 = *(const s16x8*)(buf + asidx(rr, (ks*4 + lhi)*8));
      s16x8 b1 = *(const s16x8*)(buf + asidx(rr, ((ks+4)*4 + lhi)*8));
      ca = __builtin_amdgcn_mfma_f32_16x16x32_bf16(af[ks],   b0, ca, 0, 0, 0);
      cb = __builtin_amdgcn_mfma_f32_16x16x32_bf16(af[ks+4], b1, cb, 0, 0, 0);
    }
    __builtin_amdgcn_s_setprio(0);
    return ca + cb;
  };

  // ================= head loop: stages 3h (Q), 3h+1 (K), 3h+2 (V+attn) ======
#pragma unroll 1
  for (int h = 0; h < 8; h++) {
    // ---- Q ----
    STAGE_SYNC(3*h + 1);
    {
      f32x4 c = proj((3*h) & 1);
      float bias = bqkv[0*256 + h*32 + rr];
#pragma unroll
      for (int r = 0; r < 4; r++)
        Qs[scridx(lhi*4 + r, rr)] = f2bf(c[r] + bias);
    }
    // ---- K ----
    STAGE_SYNC(3*h + 2);
    {
      f32x4 c = proj((3*h + 1) & 1);
      float bias = bqkv[1*256 + h*32 + rr];
#pragma unroll
      for (int r = 0; r < 4; r++)
        Ks[scridx(lhi*4 + r, rr)] = f2bf(c[r] + bias);
    }
    // ---- V + attention ----
    STAGE_SYNC(3*h + 3);
    {
      f32x4 c = proj((3*h + 2) & 1);
      float bias = bqkv[2*256 + h*32 + rr];
#pragma unroll
      for (int r = 0; r < 4; r++)
        Vt[scridx(rr, lhi*4 + r)] = f2bf(c[r] + bias);   // V^T [d][t]

      // scores = Q K^T / sqrt(32); wave-parallel softmax (both pair waves
      // compute identical P — benign identical-write race)
      s16x8 aq = *(const s16x8*)(Qs + scridx(llo, lhi*8));
      s16x8 bk = *(const s16x8*)(Ks + scridx(llo, lhi*8));
      f32x4 sc = __builtin_amdgcn_mfma_f32_16x16x32_bf16(aq, bk, fzero, 0, 0, 0);

      // Publication + ordering fence: (a) our Vt stores commit, (b) every
      // wave's aq/bk reads are consumed before any wave's P-store below
      // overwrites Ks (the round-3 race).
      PUB_BARRIER();

#pragma unroll
      for (int r = 0; r < 4; r++) {
        float s = sc[r] * 0.17677669529663689f;
        if (AXIS == 0) {   // two packed length-8 seqs: block-diagonal mask
          int srow = lhi*4 + r;
          if ((srow >> 3) != (llo >> 3)) s = -1e30f;
        }
        float mx = s;
        mx = fmaxf(mx, __shfl_xor(mx, 1));
        mx = fmaxf(mx, __shfl_xor(mx, 2));
        mx = fmaxf(mx, __shfl_xor(mx, 4));
        mx = fmaxf(mx, __shfl_xor(mx, 8));
        float e = __expf(s - mx);
        float sm = e;
        sm += __shfl_xor(sm, 1);
        sm += __shfl_xor(sm, 2);
        sm += __shfl_xor(sm, 4);
        sm += __shfl_xor(sm, 8);
        Ks[scridx(lhi*4 + r, llo)] = f2bf(e * __builtin_amdgcn_rcpf(sm)); // P
      }
      // PV: own d-half only (P k-pad garbage × V^T zero-pad = 0)
      s16x8 ap = *(const s16x8*)(Ks + scridx(llo, lhi*8));
      s16x8 bv = *(const s16x8*)(Vt + scridx(rr, lhi*8));
      f32x4 o = __builtin_amdgcn_mfma_f32_16x16x32_bf16(ap, bv, fzero, 0, 0, 0);
#pragma unroll
      for (int r = 0; r < 4; r++)
        As[asidx(pr*16 + lhi*4 + r, h*32 + rr)] = f2bf(o[r]);
    }
  }

  // ================= out-proj: stages 24..31, acc += A @ Wo ==================
  f32x4 acc[8];
#pragma unroll 1
  for (int st = 0; st < 8; st++) {
    STAGE_SYNC(25 + st);
    if (st == 0) {
      // reload A-fragments = per-token attn outputs (all heads)
#pragma unroll
      for (int ks = 0; ks < 8; ks++)
        af[ks] = *(const s16x8*)(As + asidx(xrow, (ks*4 + lhi)*8));
#pragma unroll
      for (int i = 0; i < 8; i++) acc[i] = fzero;
    }
    {
      const ushort* buf = (st & 1) ? Wb1 : Wb0;
      f32x4 t0 = fzero;
      __builtin_amdgcn_s_setprio(1);
#pragma unroll
      for (int ks = 0; ks < 4; ks++) {
        s16x8 b0 = *(const s16x8*)(buf + asidx(rr, (ks*4 + lhi)*8));
        s16x8 b1 = *(const s16x8*)(buf + asidx(rr, ((ks+4)*4 + lhi)*8));
        acc[st] = __builtin_amdgcn_mfma_f32_16x16x32_bf16(af[ks],   b0, acc[st], 0, 0, 0);
        t0      = __builtin_amdgcn_mfma_f32_16x16x32_bf16(af[ks+4], b1, t0,      0, 0, 0);
      }
      __builtin_amdgcn_s_setprio(0);
      acc[st] = acc[st] + t0;
    }
  }

  // ======== vectorized epilogue: transpose acc through LDS, float4 RMW ======
  // Wbuf+As (first 64 KB) are dead -> fp32 [64][256] staging tile.
  float* Fep = (float*)smem;
  PUB_BARRIER();   // all waves' final weight/As ds_reads complete
#pragma unroll
  for (int st = 0; st < 8; st++) {
#pragma unroll
    for (int r = 0; r < 4; r++) {
      int row = pr*16 + lhi*4 + r;
      Fep[epidx(row, st*32 + half*16 + llo)] = acc[st][r];
    }
  }
  PUB_BARRIER();   // acc tile published
  {
    int row = tid >> 3, g = tid & 7;
    int tok = token_index<AXIS>(blk, row);
    size_t base = (size_t)tok*256;
#pragma unroll
    for (int i = 0; i < 8; i++) {
      int f = i*32 + g*4;
      float4 v = *(float4*)&Fep[epidx(row, f)];
      float4 b = *(const float4*)&bo[f];
      v.x += b.x; v.y += b.y; v.z += b.z; v.w += b.w;
      if (AXIS == 0) {
        float4 x = *(const float4*)&x0[base + f];
        v.x += x.x; v.y += x.y; v.z += x.z; v.w += x.w;
        *(float4*)&out[base + f] = v;             // x1 (fp32)
        ushort4 p; p.x = f2bf(v.x); p.y = f2bf(v.y);
        p.z = f2bf(v.z); p.w = f2bf(v.w);
        *(ushort4*)&x1b[base + f] = p;            // x1 (bf16)
      } else {
        float4 o = *(float4*)&out[base + f];
        o.x += v.x; o.y += v.y; o.z += v.z; o.w += v.w;
        *(float4*)&out[base + f] = o;             // accumulate axis contribution
      }
    }
  }
#undef STAGE_SYNC
}

extern "C" void kernel_launch(void* const* d_in, const int* in_sizes, int n_in,
                              void* d_out, int out_size, void* d_ws, size_t ws_size,
                              hipStream_t stream) {
  const float* x = (const float*)d_in[0];
  ushort* wq  = (ushort*)d_ws;                 // 4*3*65536 bf16
  ushort* wo  = wq + 4*3*65536;                // 4*65536 bf16
  ushort* x1b = wo + 4*65536;                  // 65536*256 bf16
  float* out = (float*)d_out;

  WSrc wsrc;
  wsrc.p[0] = (const float*)d_in[1];  wsrc.p[1] = (const float*)d_in[3];
  wsrc.p[2] = (const float*)d_in[5];  wsrc.p[3] = (const float*)d_in[7];
  wsrc.p[4] = (const float*)d_in[9];  wsrc.p[5] = (const float*)d_in[11];
  wsrc.p[6] = (const float*)d_in[13]; wsrc.p[7] = (const float*)d_in[15];
  prep_weights<<<dim3(1024), dim3(256), 0, stream>>>(wsrc, wq, wo);

  const float* bq_t = (const float*)d_in[2];  const float* bo_t = (const float*)d_in[4];
  const float* bq_d = (const float*)d_in[6];  const float* bo_d = (const float*)d_in[8];
  const float* bq_h = (const float*)d_in[10]; const float* bo_h = (const float*)d_in[12];
  const float* bq_w = (const float*)d_in[14]; const float* bo_w = (const float*)d_in[16];

  axial_pass<0><<<dim3(1024), dim3(512), 0, stream>>>(x, nullptr, wq + 0*3*65536, bq_t, wo + 0*65536, bo_t, out, x1b);
  axial_pass<1><<<dim3(1024), dim3(512), 0, stream>>>(nullptr, x1b, wq + 1*3*65536, bq_d, wo + 1*65536, bo_d, out, nullptr);
  axial_pass<2><<<dim3(1024), dim3(512), 0, stream>>>(nullptr, x1b, wq + 2*3*65536, bq_h, wo + 2*65536, bo_h, out, nullptr);
  axial_pass<3><<<dim3(1024), dim3(512), 0, stream>>>(nullptr, x1b, wq + 3*3*65536, bq_w, wo + 3*65536, bo_w, out, nullptr);
}